// Round 1
// baseline (256.942 us; speedup 1.0000x reference)
//
#include <hip/hip_runtime.h>

#define B_   8
#define T_   4096
#define D_   1024
#define E_   100
#define EP_  128
#define NTOK (B_*T_)
#define TC_  4            // t-chunks in k_feat

typedef short bf16x8 __attribute__((ext_vector_type(8)));
typedef float f32x4  __attribute__((ext_vector_type(4)));

__device__ __forceinline__ unsigned short f2b(float f){
    union { float f; unsigned int i; } v; v.f = f;
    unsigned int x = v.i;
    return (unsigned short)((x + 0x7fffu + ((x >> 16) & 1u)) >> 16);
}
__device__ __forceinline__ uint4 pack8(float4 a, float4 b){
    uint4 r;
    r.x = (unsigned int)f2b(a.x) | ((unsigned int)f2b(a.y) << 16);
    r.y = (unsigned int)f2b(a.z) | ((unsigned int)f2b(a.w) << 16);
    r.z = (unsigned int)f2b(b.x) | ((unsigned int)f2b(b.y) << 16);
    r.w = (unsigned int)f2b(b.z) | ((unsigned int)f2b(b.w) << 16);
    return r;
}
__device__ __forceinline__ void dma16(const unsigned short* g, unsigned short* l){
    __builtin_amdgcn_global_load_lds(
        (const __attribute__((address_space(1))) unsigned int*)(const void*)g,
        (__attribute__((address_space(3))) unsigned int*)(void*)l,
        16, 0, 0);
}

// ---------------- K1: normalize centroids (fp32 in) -> cn[EP_][D_] bf16 --------
__global__ __launch_bounds__(256) void k_cnorm(const float* __restrict__ cent,
                                               unsigned short* __restrict__ cn){
    const int e = blockIdx.x, tid = threadIdx.x;
    if (e >= E_){
        ((uint2*)(cn + (size_t)e*D_))[tid] = make_uint2(0u, 0u);
        return;
    }
    float4 x = ((const float4*)(cent + (size_t)e*D_))[tid];
    float ss = x.x*x.x + x.y*x.y + x.z*x.z + x.w*x.w;
    __shared__ float red[256];
    red[tid] = ss; __syncthreads();
    for (int s = 128; s > 0; s >>= 1){ if (tid < s) red[tid] += red[tid+s]; __syncthreads(); }
    float inv = 1.0f / fmaxf(sqrtf(red[0]), 1e-12f);
    unsigned int lo = (unsigned int)f2b(x.x*inv) | ((unsigned int)f2b(x.y*inv) << 16);
    unsigned int hi = (unsigned int)f2b(x.z*inv) | ((unsigned int)f2b(x.w*inv) << 16);
    ((uint2*)(cn + (size_t)e*D_))[tid] = make_uint2(lo, hi);
}

// ---------------- K2: fused prep + sim GEMM + register softmax -----------------
// grid = NTOK/32 = 1024 blocks (4/CU @ 40KB LDS), 256 threads. Tile 32t x 128e.
// A-operand: fp32 tokens -> reg -> (ss accumulate) -> bf16 -> swizzled ds_write.
// B-operand: bf16 cn via global_load_lds DMA (L2-resident).
__global__ __launch_bounds__(256) void k_sim(const float* __restrict__ tokens,
                                             const unsigned short* __restrict__ cn,
                                             float* __restrict__ out_assign,
                                             unsigned short* __restrict__ pT,
                                             float* __restrict__ wpart){
    __shared__ __align__(16) char smem[40960];
    unsigned short* aBuf[2] = {(unsigned short*)smem, (unsigned short*)(smem + 4096)};
    unsigned short* bBuf[2] = {(unsigned short*)(smem + 8192), (unsigned short*)(smem + 8192 + 16384)};

    const int tid = threadIdx.x;
    const int t0  = blockIdx.x * 32;
    const int bb  = t0 >> 12;
    const int tl0 = t0 & (T_ - 1);
    const int lane = tid & 63, w = tid >> 6;
    const int wm = w >> 1, wn = w & 1, lrow = lane & 15, quad = lane >> 4;

    // A reg-staging: thread owns row ra (0..31), 8-half block ga of each 64-chunk.
    // LDS slot s holds global block s^(row&7)  (same swizzle as before).
    const int ra = tid >> 3;
    const int ga = tid & 7;
    const int sa = ga ^ (ra & 7);
    const float* gA = tokens + (size_t)(t0 + ra)*D_ + ga*8;
    unsigned short* lA[2] = { aBuf[0] + ra*64 + sa*8, aBuf[1] + ra*64 + sa*8 };

    // B DMA: wave w fills chunks c=4w..4w+3 (rows 8c..8c+7 each).
    const unsigned short* gB[4];
    unsigned short* lB[2][4];
    #pragma unroll
    for (int j = 0; j < 4; j++){
        int c = 4*w + j;
        int brow = 8*c + (lane >> 3);
        int bjg  = (lane & 7) ^ (brow & 7);
        gB[j] = cn + (size_t)brow*D_ + bjg*8;
        lB[0][j] = bBuf[0] + c*512;
        lB[1][j] = bBuf[1] + c*512;
    }

    f32x4 acc[4];
    #pragma unroll
    for (int j = 0; j < 4; j++) acc[j] = (f32x4){0.f,0.f,0.f,0.f};

    // prologue: chunk 0
    float ss = 0.f;
    float4 a0 = *(const float4*)(gA);
    float4 a1 = *(const float4*)(gA + 4);
    ss += a0.x*a0.x + a0.y*a0.y + a0.z*a0.z + a0.w*a0.w
        + a1.x*a1.x + a1.y*a1.y + a1.z*a1.z + a1.w*a1.w;
    *(uint4*)lA[0] = pack8(a0, a1);
    #pragma unroll
    for (int j = 0; j < 4; j++) dma16(gB[j], lB[0][j]);

    for (int ki = 0; ki < 16; ki++){
        const int cur = ki & 1;
        __syncthreads();                      // cur buffer complete (vmcnt0 + lgkm + barrier)
        if (ki < 15){
            const int k0 = (ki + 1) * 64;
            #pragma unroll
            for (int j = 0; j < 4; j++) dma16(gB[j] + k0, lB[1 - cur][j]);  // fly during MFMA
            a0 = *(const float4*)(gA + k0);   // A prefetch to regs; latency hidden by MFMA
            a1 = *(const float4*)(gA + k0 + 4);
        }
        const unsigned short* aC = aBuf[cur];
        const unsigned short* bC = bBuf[cur];
        #pragma unroll
        for (int kk = 0; kk < 2; kk++){
            const int b = quad + 4*kk;
            const int m = wm*16 + lrow;
            bf16x8 af = *(const bf16x8*)(aC + m*64 + ((b ^ (m & 7)) * 8));
            #pragma unroll
            for (int ni = 0; ni < 4; ni++){
                const int n = wn*64 + ni*16 + lrow;
                bf16x8 bfr = *(const bf16x8*)(bC + n*64 + ((b ^ (n & 7)) * 8));
                acc[ni] = __builtin_amdgcn_mfma_f32_16x16x32_bf16(af, bfr, acc[ni], 0, 0, 0);
            }
        }
        if (ki < 15){
            ss += a0.x*a0.x + a0.y*a0.y + a0.z*a0.z + a0.w*a0.w
                + a1.x*a1.x + a1.y*a1.y + a1.z*a1.z + a1.w*a1.w;
            *(uint4*)lA[1 - cur] = pack8(a0, a1);   // into next buffer: safe post-barrier
        }
    }
    __syncthreads();   // all MFMA reads done; smem reusable

    // overlays
    float* cmA  = (float*)smem;               // [32][2]
    float* csA  = (float*)(smem + 256);       // [32][2]
    float* wsum = (float*)(smem + 512);       // [128]
    float* scL  = (float*)(smem + 1024);      // [32] per-row 1/(max(||x||,eps)*TEMP)
    unsigned short* spT = (unsigned short*)(smem + 8192);  // [128][40]

    // finish row norms: 8 lanes per row (contiguous) hold partials
    ss += __shfl_xor(ss, 1); ss += __shfl_xor(ss, 2); ss += __shfl_xor(ss, 4);
    if (ga == 0) scL[ra] = 10.0f / fmaxf(sqrtf(ss), 1e-12f);
    if (tid < 128) wsum[tid] = 0.f;
    __syncthreads();

    // scale by norms, row max+sum via 16-lane shuffles
    float rm[4], rs[4];
    #pragma unroll
    for (int rr = 0; rr < 4; rr++){
        const int row = wm*16 + quad*4 + rr;
        const float sc = scL[row];
        float m = -1e30f;
        #pragma unroll
        for (int ni = 0; ni < 4; ni++){
            const int col = wn*64 + ni*16 + lrow;
            float v = acc[ni][rr] * sc;
            acc[ni][rr] = v;
            if (col < E_) m = fmaxf(m, v);
        }
        #pragma unroll
        for (int off = 1; off < 16; off <<= 1) m = fmaxf(m, __shfl_xor(m, off));
        float s = 0.f;
        #pragma unroll
        for (int ni = 0; ni < 4; ni++){
            const int col = wn*64 + ni*16 + lrow;
            s += (col < E_) ? __expf(acc[ni][rr] - m) : 0.f;
        }
        #pragma unroll
        for (int off = 1; off < 16; off <<= 1) s += __shfl_xor(s, off);
        rm[rr] = m; rs[rr] = s;
    }
    if (lrow == 0){
        #pragma unroll
        for (int rr = 0; rr < 4; rr++){
            const int row = wm*16 + quad*4 + rr;
            cmA[row*2 + wn] = rm[rr];
            csA[row*2 + wn] = rs[rr];
        }
    }
    __syncthreads();

    // final p; fp32 out_assign; bf16 transpose tile; weight partials
    float wp[4] = {0.f, 0.f, 0.f, 0.f};
    #pragma unroll
    for (int rr = 0; rr < 4; rr++){
        const int row = wm*16 + quad*4 + rr;
        const float m0 = cmA[row*2], m1 = cmA[row*2 + 1];
        const float M  = fmaxf(m0, m1);
        const float S  = csA[row*2]*__expf(m0 - M) + csA[row*2 + 1]*__expf(m1 - M);
        const float rinv = 1.0f / S;
        #pragma unroll
        for (int ni = 0; ni < 4; ni++){
            const int col = wn*64 + ni*16 + lrow;
            float p = 0.f;
            if (col < E_){
                p = __expf(acc[ni][rr] - M) * rinv;
                out_assign[(size_t)(t0 + row)*E_ + col] = p;
                wp[ni] += p;
            }
            spT[col*40 + row] = f2b(p);
        }
    }
    #pragma unroll
    for (int ni = 0; ni < 4; ni++){
        const int col = wn*64 + ni*16 + lrow;
        float v = wp[ni];
        v += __shfl_xor(v, 16);
        v += __shfl_xor(v, 32);
        if (quad == 0 && col < E_) atomicAdd(&wsum[col], v);   // LDS atomic
    }
    __syncthreads();

    // coalesced pT store + weight partial store
    #pragma unroll
    for (int j = 0; j < 2; j++){
        const int i = tid + 256*j;
        const int e = i >> 2;
        const int o = (i & 3) * 8;
        uint4 v = *(const uint4*)(spT + e*40 + o);
        *(uint4*)(pT + ((size_t)bb*EP_ + e)*T_ + tl0 + o) = v;
    }
    if (tid < 128) wpart[((size_t)bb*EP_ + (tl0 >> 5))*EP_ + tid] = wsum[tid];
}

// ---------------- K3: partial entity_features (fp32 tokens, cvt in repack) -----
// grid = (16 d-tiles, TC_ t-chunks, 8 batches) = 512 blocks. Tile 128e x 64d.
__global__ __launch_bounds__(256) void k_feat(const float* __restrict__ tokens,
                                              const unsigned short* __restrict__ pT,
                                              float* __restrict__ facc_part){
    const int tid = threadIdx.x;
    const int d0  = blockIdx.x * 64;
    const int tc  = blockIdx.y;
    const int bb  = blockIdx.z;
    const int KT  = T_ / TC_;       // 1024

    __shared__ __align__(16) unsigned short lds_a[128*72];   // [e][t]
    __shared__ __align__(16) unsigned short lds_bt[64*72];   // [d][t]

    const unsigned short* gA[4]; unsigned short* sA[4];
    #pragma unroll
    for (int j = 0; j < 4; j++){
        int row = (tid >> 3) + 32*j;
        gA[j] = pT + ((size_t)bb*EP_ + row)*T_ + tc*KT + (tid & 7)*8;
        sA[j] = lds_a + row*72 + (tid & 7)*8;
    }
    const int trow = tid >> 2, dseg = tid & 3;
    const float* gB = tokens + ((size_t)(bb*T_ + tc*KT + trow))*D_ + d0 + dseg*16;

    const int lane = tid & 63, w = tid >> 6;
    const int wm = w >> 1, wn = w & 1, lrow = lane & 15, quad = lane >> 4;

    f32x4 acc[4][2];
    #pragma unroll
    for (int i = 0; i < 4; i++)
        #pragma unroll
        for (int j = 0; j < 2; j++) acc[i][j] = (f32x4){0.f,0.f,0.f,0.f};

    for (int kt0 = 0; kt0 < KT; kt0 += 64){
        #pragma unroll
        for (int j = 0; j < 4; j++)
            *(uint4*)(sA[j]) = *(const uint4*)(gA[j] + kt0);
        {
            float4 u0 = *(const float4*)(gB + (size_t)kt0*D_);
            float4 u1 = *(const float4*)(gB + (size_t)kt0*D_ + 4);
            float4 u2 = *(const float4*)(gB + (size_t)kt0*D_ + 8);
            float4 u3 = *(const float4*)(gB + (size_t)kt0*D_ + 12);
            const float ff[16] = {u0.x,u0.y,u0.z,u0.w, u1.x,u1.y,u1.z,u1.w,
                                  u2.x,u2.y,u2.z,u2.w, u3.x,u3.y,u3.z,u3.w};
            #pragma unroll
            for (int q = 0; q < 8; q++){
                int dloc = dseg*16 + q*2;
                lds_bt[(dloc+0)*72 + trow] = f2b(ff[2*q]);
                lds_bt[(dloc+1)*72 + trow] = f2b(ff[2*q+1]);
            }
        }
        __syncthreads();
        #pragma unroll
        for (int kk = 0; kk < 64; kk += 32){
            bf16x8 af[4], bfr[2];
            #pragma unroll
            for (int mi = 0; mi < 4; mi++)
                af[mi] = *(const bf16x8*)(lds_a + (wm*64 + mi*16 + lrow)*72 + kk + quad*8);
            #pragma unroll
            for (int ni = 0; ni < 2; ni++)
                bfr[ni] = *(const bf16x8*)(lds_bt + (wn*32 + ni*16 + lrow)*72 + kk + quad*8);
            #pragma unroll
            for (int mi = 0; mi < 4; mi++)
                #pragma unroll
                for (int ni = 0; ni < 2; ni++)
                    acc[mi][ni] = __builtin_amdgcn_mfma_f32_16x16x32_bf16(af[mi], bfr[ni], acc[mi][ni], 0, 0, 0);
        }
        __syncthreads();
    }

    #pragma unroll
    for (int mi = 0; mi < 4; mi++){
        #pragma unroll
        for (int ni = 0; ni < 2; ni++){
            int d = d0 + wn*32 + ni*16 + lrow;
            #pragma unroll
            for (int rr = 0; rr < 4; rr++){
                int e = wm*64 + mi*16 + quad*4 + rr;
                if (e < E_)
                    facc_part[((size_t)(tc*B_ + bb)*E_ + e)*D_ + d] = acc[mi][ni][rr];
            }
        }
    }
}

// ---------------- K4: w = sum chunks; out = (sum parts)/(w+eps) ----------------
// grid = (E_, B_), 256 threads.
__global__ __launch_bounds__(256) void k_final(const float* __restrict__ wpart,
                                               const float* __restrict__ facc_part,
                                               float* __restrict__ out_feat){
    const int e  = blockIdx.x;
    const int bb = blockIdx.y;
    const int tid = threadIdx.x;

    __shared__ float red[128];
    if (tid < 128) red[tid] = wpart[((size_t)bb*EP_ + tid)*EP_ + e];
    __syncthreads();
    for (int st = 64; st > 0; st >>= 1){ if (tid < st) red[tid] += red[tid+st]; __syncthreads(); }
    const float winv = 1.0f / (red[0] + 1e-6f);

    const int d = tid * 4;
    float4 o = make_float4(0.f, 0.f, 0.f, 0.f);
    #pragma unroll
    for (int tc = 0; tc < TC_; tc++){
        float4 p = *(const float4*)(facc_part + ((size_t)(tc*B_ + bb)*E_ + e)*D_ + d);
        o.x += p.x; o.y += p.y; o.z += p.z; o.w += p.w;
    }
    o.x *= winv; o.y *= winv; o.z *= winv; o.w *= winv;
    *(float4*)(out_feat + ((size_t)bb*E_ + e)*D_ + d) = o;
}

extern "C" void kernel_launch(void* const* d_in, const int* in_sizes, int n_in,
                              void* d_out, int out_size, void* d_ws, size_t ws_size,
                              hipStream_t stream){
    const float* tokens = (const float*)d_in[0];
    const float* cent   = (const float*)d_in[1];
    float* out        = (float*)d_out;
    float* out_assign = out;
    float* out_feat   = out + (size_t)B_*T_*E_;

    float* wpart = (float*)d_ws;                                      // B*128*128 f32
    float* facc_part = wpart + (size_t)B_*EP_*EP_;                    // TC_*B*E*D f32
    unsigned short* cn = (unsigned short*)(facc_part + (size_t)TC_*B_*E_*D_);  // EP_*D_ bf16
    unsigned short* pT = cn + (size_t)EP_*D_;                         // B_*EP_*T_ bf16

    k_cnorm<<<EP_, 256, 0, stream>>>(cent, cn);
    k_sim  <<<NTOK/32, 256, 0, stream>>>(tokens, cn, out_assign, pT, wpart);
    k_feat <<<dim3(16, TC_, B_), 256, 0, stream>>>(tokens, pT, facc_part);
    k_final<<<dim3(E_, B_), 256, 0, stream>>>(wpart, facc_part, out_feat);
}